// Round 16
// baseline (4988.753 us; speedup 1.0000x reference)
//
#include <hip/hip_runtime.h>
#include <math.h>

#define N_LAYER 4
#define N_HEAD  12
#define D_MODEL 768
#define SEQ     2048
#define VOCAB   50257
#define BATCH   2
#define MROWS   (BATCH*SEQ)   // 4096

typedef __bf16 bf16;
typedef __bf16 bf16x8 __attribute__((ext_vector_type(8)));
typedef float  f32x4  __attribute__((ext_vector_type(4)));
typedef short  short8v __attribute__((ext_vector_type(8)));

__device__ __forceinline__ void gload16(const bf16* g, const bf16* l) {
    __builtin_amdgcn_global_load_lds(
        (const __attribute__((address_space(1))) void*)g,
        (__attribute__((address_space(3))) void*)l,
        16, 0, 0);
}

// ---------------------------------------------------------------- embedding
__global__ __launch_bounds__(256) void embed_kernel(
    const int* __restrict__ feat, const float* __restrict__ tok,
    const float* __restrict__ pos, float* __restrict__ x)
{
    int row = blockIdx.x;                // 0..4095
    int cpos = row & (SEQ - 1);
    int tid = feat[row];
    const float* te = tok + (size_t)tid * D_MODEL;
    const float* pe = pos + (size_t)cpos * D_MODEL;
    float* xr = x + (size_t)row * D_MODEL;
    for (int c = threadIdx.x; c < D_MODEL; c += 256)
        xr[c] = te[c] + pe[c];
}

// ---------------------------------------------------------------- layernorm -> bf16 (wave-per-row, no barriers)
__global__ __launch_bounds__(256) void ln_kernel(
    const float* __restrict__ x, const float* __restrict__ w,
    const float* __restrict__ b, bf16* __restrict__ out)
{
    int wid = threadIdx.x >> 6, lane = threadIdx.x & 63;
    int row = blockIdx.x * 4 + wid;
    const float* xr = x + (size_t)row * D_MODEL;
    float lv[12];
    float s = 0.f, ss = 0.f;
#pragma unroll
    for (int i = 0; i < 12; i++) {
        float v = xr[lane + i * 64];
        lv[i] = v; s += v; ss += v * v;
    }
#pragma unroll
    for (int o = 32; o; o >>= 1) { s += __shfl_down(s, o, 64); ss += __shfl_down(ss, o, 64); }
    s = __shfl(s, 0, 64); ss = __shfl(ss, 0, 64);
    float mu  = s * (1.f / D_MODEL);
    float var = ss * (1.f / D_MODEL) - mu * mu;
    float rs  = rsqrtf(var + 1e-5f);
#pragma unroll
    for (int i = 0; i < 12; i++) {
        int c = lane + i * 64;
        out[(size_t)row * D_MODEL + c] = (bf16)((lv[i] - mu) * rs * w[c] + b[c]);
    }
}

// ---------------------------------------------------------------- W [K,N] f32 -> Wt [N,K] bf16
__global__ __launch_bounds__(256) void transpose_conv_kernel(
    const float* __restrict__ W, bf16* __restrict__ Wt, int K, int N)
{
    int l = blockIdx.z;
    const float* Wl = W + (size_t)l * K * N;
    bf16* Wtl = Wt + (size_t)l * K * N;
    __shared__ float tile[32][33];
    int k0 = blockIdx.y * 32, n0 = blockIdx.x * 32;
    for (int idx = threadIdx.x; idx < 1024; idx += 256) {
        int i = idx >> 5, j = idx & 31;
        int n = n0 + j;
        tile[i][j] = (n < N) ? Wl[(size_t)(k0 + i) * N + n] : 0.f;
    }
    __syncthreads();
    for (int idx = threadIdx.x; idx < 1024; idx += 256) {
        int j = idx >> 5, i = idx & 31;
        int n = n0 + j;
        if (n < N) Wtl[(size_t)n * K + k0 + i] = (bf16)tile[i][j];
    }
}

// ---------------------------------------------------------------- layer GEMM: 128x128, BK=32, dbuf + counted vmcnt
// (R11-proven: 32KB LDS -> 4-5 blocks/CU co-residency).
// OUTM: 1 = bias bf16 store, 2 = f32 residual add (atomic when SPLITK>1),
//       3 = QKV: Q,K cols -> big; V cols -> vT[b][h][d][s] (fused V-transpose)
template<bool BIAS, bool GELU_, int OUTM, int SPLITK>
__global__ __launch_bounds__(256) void gemm_kernel(
    const bf16* __restrict__ A, const bf16* __restrict__ Bt,
    const float* __restrict__ bias, void* __restrict__ Cout,
    bf16* __restrict__ vTout,
    int M, int N, int K)
{
    __shared__ __align__(16) bf16 As[2][128 * 32];
    __shared__ __align__(16) bf16 Bs[2][128 * 32];
    int tid = threadIdx.x;
    int lane = tid & 63, wid = tid >> 6;

    int Kslice = K / SPLITK;
    int kbase = (SPLITK > 1) ? (int)blockIdx.z * Kslice : 0;

    int row0 = blockIdx.x * 128;
    int col0 = blockIdx.y * 128;

    int wr = (wid >> 1) * 64, wc = (wid & 1) * 64;

    int srow = wid * 16 + (lane >> 2);
    int selem = (lane & 3) * 8;
    const bf16* Ab0 = A + (size_t)(row0 + srow) * K + kbase + selem;
    const bf16* Ab1 = Ab0 + (size_t)64 * K;
    int bn0 = col0 + srow;      if (bn0 >= N) bn0 = N - 1;
    int bn1 = col0 + srow + 64; if (bn1 >= N) bn1 = N - 1;
    const bf16* Bb0 = Bt + (size_t)bn0 * K + kbase + selem;
    const bf16* Bb1 = Bt + (size_t)bn1 * K + kbase + selem;

    const int nt = Kslice >> 5;
    int fr = lane & 15, fg8 = (lane >> 4) * 8;

    auto stage = [&](int t, int b) {
        int k0 = t * 32;
        gload16(Ab0 + k0, As[b] + wid * 512);
        gload16(Ab1 + k0, As[b] + (wid + 4) * 512);
        gload16(Bb0 + k0, Bs[b] + wid * 512);
        gload16(Bb1 + k0, Bs[b] + (wid + 4) * 512);
    };

    f32x4 acc[4][4] = {};
    stage(0, 0);

    for (int t = 0; t < nt; ++t) {
        int cur = t & 1;
        if (t + 1 < nt) {
            stage(t + 1, cur ^ 1);
            asm volatile("s_waitcnt vmcnt(4)" ::: "memory");
        } else {
            asm volatile("s_waitcnt vmcnt(0)" ::: "memory");
        }
        __builtin_amdgcn_s_barrier();

        bf16x8 af[4], bfr[4];
#pragma unroll
        for (int m = 0; m < 4; m++) af[m] = *(const bf16x8*)&As[cur][(wr + m * 16 + fr) * 32 + fg8];
#pragma unroll
        for (int n = 0; n < 4; n++) bfr[n] = *(const bf16x8*)&Bs[cur][(wc + n * 16 + fr) * 32 + fg8];
#pragma unroll
        for (int m = 0; m < 4; m++)
#pragma unroll
            for (int n = 0; n < 4; n++)
                acc[m][n] = __builtin_amdgcn_mfma_f32_16x16x32_bf16(af[m], bfr[n], acc[m][n], 0, 0, 0);

        asm volatile("s_waitcnt lgkmcnt(0)" ::: "memory");
        __builtin_amdgcn_s_barrier();
    }

    int g = lane >> 4;
    bool addbias = BIAS && (SPLITK == 1 || blockIdx.z == 0);

#pragma unroll
    for (int m = 0; m < 4; m++) {
#pragma unroll
        for (int n = 0; n < 4; n++) {
            int col = col0 + wc + n * 16 + fr;
            bool ok = (col < N);
            float bv = (addbias && ok) ? bias[col] : 0.f;
#pragma unroll
            for (int r = 0; r < 4; r++) {
                int row = row0 + wr + m * 16 + g * 4 + r;
                float v = acc[m][n][r] + bv;
                if (GELU_) v = 0.5f * v * (1.f + erff(v * 0.70710678118f));
                if (ok) {
                    if (OUTM == 1)
                        ((bf16*)Cout)[(size_t)row * N + col] = (bf16)v;
                    else if (OUTM == 3) {
                        if (col < 2 * D_MODEL) {
                            ((bf16*)Cout)[(size_t)row * N + col] = (bf16)v;
                        } else {
                            int c2 = col - 2 * D_MODEL;
                            int hh = c2 >> 6, dd = c2 & 63;
                            int bb = row >> 11, ss = row & (SEQ - 1);
                            vTout[(((size_t)(bb * N_HEAD + hh) * 64 + dd) << 11) + ss] = (bf16)v;
                        }
                    }
                    else if (SPLITK > 1)
                        atomicAdd(&((float*)Cout)[(size_t)row * N + col], v);
                    else
                        ((float*)Cout)[(size_t)row * N + col] += v;
                }
            }
        }
    }
}

// ---------------------------------------------------------------- logits GEMM: 256x256 tile, 8 waves, BK=64,
// SINGLE-buffered LDS (64KB -> 2 blocks/CU; cross-block TLP hides stage+epilogue),
// 2 barriers/K-tile, setprio around MFMA, fused LSE,
// full 3-bit XOR swizzle (R11-proven conflict-free).
__global__ __launch_bounds__(512, 4) void gemm256_logits_kernel(
    const bf16* __restrict__ A, const bf16* __restrict__ Bt,
    float* __restrict__ Cout, float* __restrict__ rowsum, int N, int K)
{
    __shared__ __align__(16) bf16 As[256 * 64];
    __shared__ __align__(16) bf16 Bs[256 * 64];
    int tid = threadIdx.x, lane = tid & 63, wid = tid >> 6;
    int wm = wid >> 2, wn = wid & 3;           // 2 x 4 wave grid; wave owns 128x64
    int row0 = blockIdx.x * 256, col0 = blockIdx.y * 256;
    int fr = lane & 15, fg8 = (lane >> 4) * 8, g = lane >> 4;

    int srow_c = lane >> 3;                    // row within 8-row chunk (0..7)
    int scol   = ((lane & 7) ^ srow_c) * 8;    // pre-swizzled global source col
    int sw     = (fr & 7) << 3;
    int cswz0  = (0 * 32 + fg8) ^ sw;
    int cswz1  = (1 * 32 + fg8) ^ sw;

    const int nt = K >> 6;                     // 12 K-tiles

    auto stage = [&](int t) {
        int k0 = t * 64;
#pragma unroll
        for (int j = 0; j < 4; j++) {
            int rloc = (wid * 4 + j) * 8;      // 8 waves x 4 x 8 rows = 256
            gload16(A + (size_t)(row0 + rloc + srow_c) * K + k0 + scol,
                    As + rloc * 64);
            int grow = col0 + rloc + srow_c;
            if (grow >= N) grow = N - 1;
            gload16(Bt + (size_t)grow * K + k0 + scol,
                    Bs + rloc * 64);
        }
    };

    f32x4 acc[8][4] = {};

    for (int t = 0; t < nt; ++t) {
        stage(t);
        asm volatile("s_waitcnt vmcnt(0)" ::: "memory");
        __builtin_amdgcn_s_barrier();

        bf16x8 bfrag[4][2];
#pragma unroll
        for (int n = 0; n < 4; n++) {
            bfrag[n][0] = *(const bf16x8*)&Bs[(wn * 64 + n * 16 + fr) * 64 + cswz0];
            bfrag[n][1] = *(const bf16x8*)&Bs[(wn * 64 + n * 16 + fr) * 64 + cswz1];
        }
        __builtin_amdgcn_s_setprio(1);
#pragma unroll
        for (int mf = 0; mf < 8; mf++) {
            bf16x8 a0 = *(const bf16x8*)&As[(wm * 128 + mf * 16 + fr) * 64 + cswz0];
            bf16x8 a1 = *(const bf16x8*)&As[(wm * 128 + mf * 16 + fr) * 64 + cswz1];
#pragma unroll
            for (int n = 0; n < 4; n++) {
                acc[mf][n] = __builtin_amdgcn_mfma_f32_16x16x32_bf16(a0, bfrag[n][0], acc[mf][n], 0, 0, 0);
                acc[mf][n] = __builtin_amdgcn_mfma_f32_16x16x32_bf16(a1, bfrag[n][1], acc[mf][n], 0, 0, 0);
            }
        }
        __builtin_amdgcn_s_setprio(0);
        asm volatile("s_waitcnt lgkmcnt(0)" ::: "memory");
        __builtin_amdgcn_s_barrier();
    }

    // -------- epilogue: store f32 logits + fused sum(exp) per row
#pragma unroll
    for (int mf = 0; mf < 8; mf++) {
        float lsum[4] = {0.f, 0.f, 0.f, 0.f};
#pragma unroll
        for (int n = 0; n < 4; n++) {
            int col = col0 + wn * 64 + n * 16 + fr;
            bool ok = (col < N);
#pragma unroll
            for (int r = 0; r < 4; r++) {
                int row = row0 + wm * 128 + mf * 16 + g * 4 + r;
                float v = acc[mf][n][r];
                if (ok) {
                    Cout[(size_t)row * N + col] = v;
                    lsum[r] += __expf(v);
                }
            }
        }
#pragma unroll
        for (int r = 0; r < 4; r++) {
            float s = lsum[r];
#pragma unroll
            for (int o = 1; o < 16; o <<= 1) s += __shfl_xor(s, o, 64);
            if (fr == 0)
                atomicAdd(&rowsum[row0 + wm * 128 + mf * 16 + g * 4 + r], s);
        }
    }
}

// ---------------------------------------------------------------- flash attention (barrier-free)
__global__ __launch_bounds__(256) void attn_kernel(
    const bf16* __restrict__ qkv, const bf16* __restrict__ vT, bf16* __restrict__ y)
{
    int qt = (int)(gridDim.x - 1 - blockIdx.x), h = blockIdx.y, b = blockIdx.z;
    const size_t rs = 3 * D_MODEL;
    int tid = threadIdx.x, lane = tid & 63, wid = tid >> 6;
    int fr = lane & 15, g = lane >> 4;
    int wq = qt * 64 + wid * 16;                 // wave's q-row base

    const bf16* qb = qkv + (size_t)b * SEQ * rs + h * 64;
    const bf16* kb = qb + D_MODEL;
    const bf16* vb = vT + ((size_t)(b * N_HEAD + h) * 64) * SEQ;

    __shared__ bf16 Ps[4][16][72];

    bf16x8 aq[2];
#pragma unroll
    for (int kk = 0; kk < 2; kk++)
        aq[kk] = *(const bf16x8*)&qb[(size_t)(wq + fr) * rs + kk * 32 + g * 8];

    f32x4 acco[4] = {};
    float mrow[4], lrow[4];
#pragma unroll
    for (int r = 0; r < 4; r++) { mrow[r] = -1e30f; lrow[r] = 0.f; }

    int jmax = qt * 64;
    for (int j0 = 0; j0 <= jmax; j0 += 64) {
        f32x4 accs[4] = {};
#pragma unroll
        for (int n = 0; n < 4; n++)
#pragma unroll
            for (int kk = 0; kk < 2; kk++) {
                bf16x8 bk = *(const bf16x8*)&kb[(size_t)(j0 + n * 16 + fr) * rs + kk * 32 + g * 8];
                accs[n] = __builtin_amdgcn_mfma_f32_16x16x32_bf16(aq[kk], bk, accs[n], 0, 0, 0);
            }

        bool diag = (j0 == jmax);
#pragma unroll
        for (int n = 0; n < 4; n++) {
            int jc = j0 + n * 16 + fr;
#pragma unroll
            for (int r = 0; r < 4; r++) {
                float sv = accs[n][r] * 0.125f;
                if (diag) { int irow = wq + g * 4 + r; if (jc > irow) sv = -1e30f; }
                accs[n][r] = sv;
            }
        }

        float pscale[4];
#pragma unroll
        for (int r = 0; r < 4; r++) {
            float pm = fmaxf(fmaxf(accs[0][r], accs[1][r]), fmaxf(accs[2][r], accs[3][r]));
#pragma unroll
            for (int o = 1; o < 16; o <<= 1) pm = fmaxf(pm, __shfl_xor(pm, o, 64));
            float mnew = fmaxf(mrow[r], pm);
            float corr = __expf(mrow[r] - mnew);
            mrow[r] = mnew;
            float ls = 0.f;
#pragma unroll
            for (int n = 0; n < 4; n++) {
                float p = __expf(accs[n][r] - mnew);
                accs[n][r] = p; ls += p;
            }
#pragma unroll
            for (int o = 1; o < 16; o <<= 1) ls += __shfl_xor(ls, o, 64);
            lrow[r] = lrow[r] * corr + ls;
            pscale[r] = corr;
        }
#pragma unroll
        for (int n = 0; n < 4; n++)
#pragma unroll
            for (int r = 0; r < 4; r++) acco[n][r] *= pscale[r];

#pragma unroll
        for (int n = 0; n < 4; n++)
#pragma unroll
            for (int r = 0; r < 4; r++)
                Ps[wid][g * 4 + r][n * 16 + fr] = (bf16)accs[n][r];

        bf16x8 ap[2];
#pragma unroll
        for (int kk = 0; kk < 2; kk++)
            ap[kk] = *(const bf16x8*)&Ps[wid][fr][kk * 32 + g * 8];
#pragma unroll
        for (int kk = 0; kk < 2; kk++)
#pragma unroll
            for (int n = 0; n < 4; n++) {
                bf16x8 bv = *(const bf16x8*)&vb[(size_t)(n * 16 + fr) * SEQ + j0 + kk * 32 + g * 8];
                acco[n] = __builtin_amdgcn_mfma_f32_16x16x32_bf16(ap[kk], bv, acco[n], 0, 0, 0);
            }
    }

    bf16* yb = y + (size_t)b * SEQ * D_MODEL + h * 64;
#pragma unroll
    for (int n = 0; n < 4; n++)
#pragma unroll
        for (int r = 0; r < 4; r++) {
            int row = wq + g * 4 + r;
            yb[(size_t)row * D_MODEL + n * 16 + fr] = (bf16)(acco[n][r] / lrow[r]);
        }
}

// ---------------------------------------------------------------- loss finalize
__global__ __launch_bounds__(256) void loss_nll_kernel(
    const float* __restrict__ logits, const float* __restrict__ rowsum,
    const int* __restrict__ tgt, float* __restrict__ accum)
{
    int row = blockIdx.x * 256 + threadIdx.x;
    if (row >= MROWS) return;
    int t = tgt[row];
    if (t >= 0) {
        float nll = logf(rowsum[row]) - logits[(size_t)row * VOCAB + t];
        atomicAdd(accum, nll);
        atomicAdd(accum + 1, 1.f);
    }
}

__global__ void loss_final_kernel(const float* __restrict__ accum, float* __restrict__ out)
{
    out[0] = accum[0] / fmaxf(accum[1], 1.f);
}

// ---------------------------------------------------------------- launch
extern "C" void kernel_launch(void* const* d_in, const int* in_sizes, int n_in,
                              void* d_out, int out_size, void* d_ws, size_t ws_size,
                              hipStream_t stream)
{
    const int*   feat  = (const int*)d_in[0];
    const int*   tgt   = (const int*)d_in[1];
    const float* tok   = (const float*)d_in[2];
    const float* pos   = (const float*)d_in[3];
    const float* ln1w  = (const float*)d_in[4];
    const float* ln1b  = (const float*)d_in[5];
    const float* attnw = (const float*)d_in[6];
    const float* attnb = (const float*)d_in[7];
    const float* projw = (const float*)d_in[8];
    const float* projb = (const float*)d_in[9];
    const float* ln2w  = (const float*)d_in[10];
    const float* ln2b  = (const float*)d_in[11];
    const float* fw1   = (const float*)d_in[12];
    const float* fb1   = (const float*)d_in[13];
    const float* fw2   = (const float*)d_in[14];
    const float* fb2   = (const float*)d_in[15];
    const float* lnfw  = (const float*)d_in[16];
    const float* lnfb  = (const float*)d_in[17];
    const float* finw  = (const float*)d_in[18];

    char* ws = (char*)d_ws;
    size_t off = 0;
    auto alloc = [&](size_t bytes) -> void* {
        void* p = ws + off; off += (bytes + 255) & ~(size_t)255; return p;
    };
    float* x     = (float*)alloc((size_t)MROWS * D_MODEL * 4);
    bf16*  h     = (bf16*) alloc((size_t)MROWS * D_MODEL * 2);
    bf16*  big   = (bf16*) alloc((size_t)MROWS * 4 * D_MODEL * 2);   // qkv (3D) / ffn1 (4D)
    bf16*  ybuf  = (bf16*) alloc((size_t)MROWS * D_MODEL * 2);
    bf16*  vT    = (bf16*) alloc((size_t)BATCH * N_HEAD * 64 * SEQ * 2);
    bf16*  awt   = (bf16*) alloc((size_t)N_LAYER * 3 * D_MODEL * D_MODEL * 2);
    bf16*  pwt   = (bf16*) alloc((size_t)N_LAYER * D_MODEL * D_MODEL * 2);
    bf16*  f1wt  = (bf16*) alloc((size_t)N_LAYER * 4 * D_MODEL * D_MODEL * 2);
    bf16*  f2wt  = (bf16*) alloc((size_t)N_LAYER * 4 * D_MODEL * D_MODEL * 2);
    bf16*  fwt   = (bf16*) alloc((size_t)VOCAB * D_MODEL * 2);
    float* rowsum= (float*)alloc((size_t)MROWS * 4);
    float* accum = (float*)alloc(256);

    float* logits = (float*)d_out;
    float* lossp  = (float*)d_out + (size_t)MROWS * VOCAB;

    dim3 blk(256);
    // weight transposes (f32 [K,N] -> bf16 [N,K])
    transpose_conv_kernel<<<dim3(3 * D_MODEL / 32, D_MODEL / 32, N_LAYER), blk, 0, stream>>>(attnw, awt, D_MODEL, 3 * D_MODEL);
    transpose_conv_kernel<<<dim3(D_MODEL / 32, D_MODEL / 32, N_LAYER), blk, 0, stream>>>(projw, pwt, D_MODEL, D_MODEL);
    transpose_conv_kernel<<<dim3(4 * D_MODEL / 32, D_MODEL / 32, N_LAYER), blk, 0, stream>>>(fw1, f1wt, D_MODEL, 4 * D_MODEL);
    transpose_conv_kernel<<<dim3(D_MODEL / 32, 4 * D_MODEL / 32, N_LAYER), blk, 0, stream>>>(fw2, f2wt, 4 * D_MODEL, D_MODEL);
    transpose_conv_kernel<<<dim3((VOCAB + 31) / 32, D_MODEL / 32, 1), blk, 0, stream>>>(finw, fwt, D_MODEL, VOCAB);

    embed_kernel<<<MROWS, blk, 0, stream>>>(feat, tok, pos, x);

    for (int l = 0; l < N_LAYER; l++) {
        ln_kernel<<<MROWS / 4, blk, 0, stream>>>(x, ln1w + l * D_MODEL, ln1b + l * D_MODEL, h);
        gemm_kernel<true, false, 3, 1><<<dim3(MROWS / 128, (3 * D_MODEL) / 128), blk, 0, stream>>>(
            h, awt + (size_t)l * 3 * D_MODEL * D_MODEL, attnb + l * 3 * D_MODEL, big, vT,
            MROWS, 3 * D_MODEL, D_MODEL);
        attn_kernel<<<dim3(SEQ / 64, N_HEAD, BATCH), blk, 0, stream>>>(big, vT, ybuf);
        gemm_kernel<true, false, 2, 2><<<dim3(MROWS / 128, D_MODEL / 128, 2), blk, 0, stream>>>(
            ybuf, pwt + (size_t)l * D_MODEL * D_MODEL, projb + l * D_MODEL, x, nullptr,
            MROWS, D_MODEL, D_MODEL);
        ln_kernel<<<MROWS / 4, blk, 0, stream>>>(x, ln2w + l * D_MODEL, ln2b + l * D_MODEL, h);
        gemm_kernel<true, true, 1, 1><<<dim3(MROWS / 128, (4 * D_MODEL) / 128), blk, 0, stream>>>(
            h, f1wt + (size_t)l * 4 * D_MODEL * D_MODEL, fb1 + l * 4 * D_MODEL, big, nullptr,
            MROWS, 4 * D_MODEL, D_MODEL);
        gemm_kernel<true, false, 2, 2><<<dim3(MROWS / 128, D_MODEL / 128, 2), blk, 0, stream>>>(
            big, f2wt + (size_t)l * 4 * D_MODEL * D_MODEL, fb2 + l * D_MODEL, x, nullptr,
            MROWS, D_MODEL, 4 * D_MODEL);
    }

    ln_kernel<<<MROWS / 4, blk, 0, stream>>>(x, lnfw, lnfb, h);

    hipMemsetAsync(rowsum, 0, (size_t)MROWS * 4, stream);
    hipMemsetAsync(accum, 0, 8, stream);

    gemm256_logits_kernel<<<dim3(MROWS / 256, (VOCAB + 255) / 256), dim3(512), 0, stream>>>(
        h, fwt, logits, rowsum, VOCAB, D_MODEL);

    loss_nll_kernel<<<(MROWS + 255) / 256, blk, 0, stream>>>(logits, rowsum, tgt, accum);
    loss_final_kernel<<<1, 1, 0, stream>>>(accum, lossp);

    (void)in_sizes; (void)n_in; (void)out_size; (void)ws_size;
}

// Round 17
// 2068.429 us; speedup vs baseline: 2.4119x; 2.4119x over previous
//
#include <hip/hip_runtime.h>
#include <math.h>

#define N_LAYER 4
#define N_HEAD  12
#define D_MODEL 768
#define SEQ     2048
#define VOCAB   50257
#define BATCH   2
#define MROWS   (BATCH*SEQ)   // 4096

typedef __bf16 bf16;
typedef __bf16 bf16x8 __attribute__((ext_vector_type(8)));
typedef float  f32x4  __attribute__((ext_vector_type(4)));
typedef short  short8v __attribute__((ext_vector_type(8)));

__device__ __forceinline__ void gload16(const bf16* g, const bf16* l) {
    __builtin_amdgcn_global_load_lds(
        (const __attribute__((address_space(1))) void*)g,
        (__attribute__((address_space(3))) void*)l,
        16, 0, 0);
}

// ---------------------------------------------------------------- embedding
__global__ __launch_bounds__(256) void embed_kernel(
    const int* __restrict__ feat, const float* __restrict__ tok,
    const float* __restrict__ pos, float* __restrict__ x)
{
    int row = blockIdx.x;                // 0..4095
    int cpos = row & (SEQ - 1);
    int tid = feat[row];
    const float* te = tok + (size_t)tid * D_MODEL;
    const float* pe = pos + (size_t)cpos * D_MODEL;
    float* xr = x + (size_t)row * D_MODEL;
    for (int c = threadIdx.x; c < D_MODEL; c += 256)
        xr[c] = te[c] + pe[c];
}

// ---------------------------------------------------------------- layernorm -> bf16 (wave-per-row, no barriers)
__global__ __launch_bounds__(256) void ln_kernel(
    const float* __restrict__ x, const float* __restrict__ w,
    const float* __restrict__ b, bf16* __restrict__ out)
{
    int wid = threadIdx.x >> 6, lane = threadIdx.x & 63;
    int row = blockIdx.x * 4 + wid;
    const float* xr = x + (size_t)row * D_MODEL;
    float lv[12];
    float s = 0.f, ss = 0.f;
#pragma unroll
    for (int i = 0; i < 12; i++) {
        float v = xr[lane + i * 64];
        lv[i] = v; s += v; ss += v * v;
    }
#pragma unroll
    for (int o = 32; o; o >>= 1) { s += __shfl_down(s, o, 64); ss += __shfl_down(ss, o, 64); }
    s = __shfl(s, 0, 64); ss = __shfl(ss, 0, 64);
    float mu  = s * (1.f / D_MODEL);
    float var = ss * (1.f / D_MODEL) - mu * mu;
    float rs  = rsqrtf(var + 1e-5f);
#pragma unroll
    for (int i = 0; i < 12; i++) {
        int c = lane + i * 64;
        out[(size_t)row * D_MODEL + c] = (bf16)((lv[i] - mu) * rs * w[c] + b[c]);
    }
}

// ---------------------------------------------------------------- W [K,N] f32 -> Wt [N,K] bf16
__global__ __launch_bounds__(256) void transpose_conv_kernel(
    const float* __restrict__ W, bf16* __restrict__ Wt, int K, int N)
{
    int l = blockIdx.z;
    const float* Wl = W + (size_t)l * K * N;
    bf16* Wtl = Wt + (size_t)l * K * N;
    __shared__ float tile[32][33];
    int k0 = blockIdx.y * 32, n0 = blockIdx.x * 32;
    for (int idx = threadIdx.x; idx < 1024; idx += 256) {
        int i = idx >> 5, j = idx & 31;
        int n = n0 + j;
        tile[i][j] = (n < N) ? Wl[(size_t)(k0 + i) * N + n] : 0.f;
    }
    __syncthreads();
    for (int idx = threadIdx.x; idx < 1024; idx += 256) {
        int j = idx >> 5, i = idx & 31;
        int n = n0 + j;
        if (n < N) Wtl[(size_t)n * K + k0 + i] = (bf16)tile[i][j];
    }
}

// ---------------------------------------------------------------- layer GEMM: 128x128, BK=32, dbuf + counted vmcnt
// (R11-proven: 32KB LDS -> 4-5 blocks/CU co-residency).
// OUTM: 1 = bias bf16 store, 2 = f32 residual add (atomic when SPLITK>1),
//       3 = QKV: Q,K cols -> big; V cols -> vT[b][h][d][s] (fused V-transpose)
template<bool BIAS, bool GELU_, int OUTM, int SPLITK>
__global__ __launch_bounds__(256) void gemm_kernel(
    const bf16* __restrict__ A, const bf16* __restrict__ Bt,
    const float* __restrict__ bias, void* __restrict__ Cout,
    bf16* __restrict__ vTout,
    int M, int N, int K)
{
    __shared__ __align__(16) bf16 As[2][128 * 32];
    __shared__ __align__(16) bf16 Bs[2][128 * 32];
    int tid = threadIdx.x;
    int lane = tid & 63, wid = tid >> 6;

    int Kslice = K / SPLITK;
    int kbase = (SPLITK > 1) ? (int)blockIdx.z * Kslice : 0;

    int row0 = blockIdx.x * 128;
    int col0 = blockIdx.y * 128;

    int wr = (wid >> 1) * 64, wc = (wid & 1) * 64;

    int srow = wid * 16 + (lane >> 2);
    int selem = (lane & 3) * 8;
    const bf16* Ab0 = A + (size_t)(row0 + srow) * K + kbase + selem;
    const bf16* Ab1 = Ab0 + (size_t)64 * K;
    int bn0 = col0 + srow;      if (bn0 >= N) bn0 = N - 1;
    int bn1 = col0 + srow + 64; if (bn1 >= N) bn1 = N - 1;
    const bf16* Bb0 = Bt + (size_t)bn0 * K + kbase + selem;
    const bf16* Bb1 = Bt + (size_t)bn1 * K + kbase + selem;

    const int nt = Kslice >> 5;
    int fr = lane & 15, fg8 = (lane >> 4) * 8;

    auto stage = [&](int t, int b) {
        int k0 = t * 32;
        gload16(Ab0 + k0, As[b] + wid * 512);
        gload16(Ab1 + k0, As[b] + (wid + 4) * 512);
        gload16(Bb0 + k0, Bs[b] + wid * 512);
        gload16(Bb1 + k0, Bs[b] + (wid + 4) * 512);
    };

    f32x4 acc[4][4] = {};
    stage(0, 0);

    for (int t = 0; t < nt; ++t) {
        int cur = t & 1;
        if (t + 1 < nt) {
            stage(t + 1, cur ^ 1);
            asm volatile("s_waitcnt vmcnt(4)" ::: "memory");
        } else {
            asm volatile("s_waitcnt vmcnt(0)" ::: "memory");
        }
        __builtin_amdgcn_s_barrier();

        bf16x8 af[4], bfr[4];
#pragma unroll
        for (int m = 0; m < 4; m++) af[m] = *(const bf16x8*)&As[cur][(wr + m * 16 + fr) * 32 + fg8];
#pragma unroll
        for (int n = 0; n < 4; n++) bfr[n] = *(const bf16x8*)&Bs[cur][(wc + n * 16 + fr) * 32 + fg8];
#pragma unroll
        for (int m = 0; m < 4; m++)
#pragma unroll
            for (int n = 0; n < 4; n++)
                acc[m][n] = __builtin_amdgcn_mfma_f32_16x16x32_bf16(af[m], bfr[n], acc[m][n], 0, 0, 0);

        asm volatile("s_waitcnt lgkmcnt(0)" ::: "memory");
        __builtin_amdgcn_s_barrier();
    }

    int g = lane >> 4;
    bool addbias = BIAS && (SPLITK == 1 || blockIdx.z == 0);

#pragma unroll
    for (int m = 0; m < 4; m++) {
#pragma unroll
        for (int n = 0; n < 4; n++) {
            int col = col0 + wc + n * 16 + fr;
            bool ok = (col < N);
            float bv = (addbias && ok) ? bias[col] : 0.f;
#pragma unroll
            for (int r = 0; r < 4; r++) {
                int row = row0 + wr + m * 16 + g * 4 + r;
                float v = acc[m][n][r] + bv;
                if (GELU_) v = 0.5f * v * (1.f + erff(v * 0.70710678118f));
                if (ok) {
                    if (OUTM == 1)
                        ((bf16*)Cout)[(size_t)row * N + col] = (bf16)v;
                    else if (OUTM == 3) {
                        if (col < 2 * D_MODEL) {
                            ((bf16*)Cout)[(size_t)row * N + col] = (bf16)v;
                        } else {
                            int c2 = col - 2 * D_MODEL;
                            int hh = c2 >> 6, dd = c2 & 63;
                            int bb = row >> 11, ss = row & (SEQ - 1);
                            vTout[(((size_t)(bb * N_HEAD + hh) * 64 + dd) << 11) + ss] = (bf16)v;
                        }
                    }
                    else if (SPLITK > 1)
                        atomicAdd(&((float*)Cout)[(size_t)row * N + col], v);
                    else
                        ((float*)Cout)[(size_t)row * N + col] += v;
                }
            }
        }
    }
}

// ---------------------------------------------------------------- logits GEMM: 256x256 tile, 8 waves, BK=64,
// 4-phase K-tile schedule, dbuf LDS, counted vmcnt(4), setprio, fused LSE,
// full 3-bit XOR swizzle (R11-proven conflict-free, 108 VGPR, no spill).
__global__ __launch_bounds__(512, 2) void gemm256_logits_kernel(
    const bf16* __restrict__ A, const bf16* __restrict__ Bt,
    float* __restrict__ Cout, float* __restrict__ rowsum, int N, int K)
{
    __shared__ __align__(16) bf16 As[2][256 * 64];
    __shared__ __align__(16) bf16 Bs[2][256 * 64];
    int tid = threadIdx.x, lane = tid & 63, wid = tid >> 6;
    int wm = wid >> 2, wn = wid & 3;           // 2 x 4 wave grid; wave owns 128x64
    int row0 = blockIdx.x * 256, col0 = blockIdx.y * 256;
    int fr = lane & 15, fg8 = (lane >> 4) * 8, g = lane >> 4;

    int srow_c = lane >> 3;
    int scol   = ((lane & 7) ^ srow_c) * 8;
    int sw     = (fr & 7) << 3;
    int cswz0  = (0 * 32 + fg8) ^ sw;
    int cswz1  = (1 * 32 + fg8) ^ sw;

    const int nt = K >> 6;

    auto stageA = [&](int t, int half) {
        int buf = t & 1, k0 = t * 64;
#pragma unroll
        for (int j = 0; j < 2; j++) {
            int rloc = half * 128 + (wid * 2 + j) * 8;
            gload16(A + (size_t)(row0 + rloc + srow_c) * K + k0 + scol,
                    As[buf] + rloc * 64);
        }
    };
    auto stageB = [&](int t, int half) {
        int buf = t & 1, k0 = t * 64;
#pragma unroll
        for (int j = 0; j < 2; j++) {
            int rloc = half * 128 + (wid * 2 + j) * 8;
            int grow = col0 + rloc + srow_c;
            if (grow >= N) grow = N - 1;
            gload16(Bt + (size_t)grow * K + k0 + scol,
                    Bs[buf] + rloc * 64);
        }
    };

    f32x4 acc[8][4] = {};

    stageA(0, 0); stageA(0, 1); stageB(0, 0); stageB(0, 1);
    stageB(1, 0); stageB(1, 1);
    asm volatile("s_waitcnt vmcnt(4)" ::: "memory");
    __builtin_amdgcn_s_barrier();

    for (int t = 0; t < nt; ++t) {
        int c = t & 1;
        const bf16* Ac = As[c];
        const bf16* Bc = Bs[c];

        bf16x8 bfrag[4][2];
#pragma unroll
        for (int n = 0; n < 4; n++) {
            bfrag[n][0] = *(const bf16x8*)&Bc[(wn * 64 + n * 16 + fr) * 64 + cswz0];
            bfrag[n][1] = *(const bf16x8*)&Bc[(wn * 64 + n * 16 + fr) * 64 + cswz1];
        }
        {
            bf16x8 a_[2][2];
#pragma unroll
            for (int mi = 0; mi < 2; mi++) {
                a_[mi][0] = *(const bf16x8*)&Ac[(wm * 128 + mi * 16 + fr) * 64 + cswz0];
                a_[mi][1] = *(const bf16x8*)&Ac[(wm * 128 + mi * 16 + fr) * 64 + cswz1];
            }
            if (t + 1 < nt) stageA(t + 1, 0);
            __builtin_amdgcn_s_barrier();
            __builtin_amdgcn_s_setprio(1);
#pragma unroll
            for (int mi = 0; mi < 2; mi++)
#pragma unroll
                for (int n = 0; n < 4; n++)
#pragma unroll
                    for (int ks = 0; ks < 2; ks++)
                        acc[mi][n] = __builtin_amdgcn_mfma_f32_16x16x32_bf16(a_[mi][ks], bfrag[n][ks], acc[mi][n], 0, 0, 0);
            __builtin_amdgcn_s_setprio(0);
            __builtin_amdgcn_s_barrier();
        }
        {
            bf16x8 a_[2][2];
#pragma unroll
            for (int mi = 0; mi < 2; mi++) {
                a_[mi][0] = *(const bf16x8*)&Ac[(wm * 128 + (2 + mi) * 16 + fr) * 64 + cswz0];
                a_[mi][1] = *(const bf16x8*)&Ac[(wm * 128 + (2 + mi) * 16 + fr) * 64 + cswz1];
            }
            if (t + 1 < nt) stageA(t + 1, 1);
            if (t + 2 < nt) stageB(t + 2, 0);
            __builtin_amdgcn_s_barrier();
            __builtin_amdgcn_s_setprio(1);
#pragma unroll
            for (int mi = 0; mi < 2; mi++)
#pragma unroll
                for (int n = 0; n < 4; n++)
#pragma unroll
                    for (int ks = 0; ks < 2; ks++)
                        acc[2 + mi][n] = __builtin_amdgcn_mfma_f32_16x16x32_bf16(a_[mi][ks], bfrag[n][ks], acc[2 + mi][n], 0, 0, 0);
            __builtin_amdgcn_s_setprio(0);
            __builtin_amdgcn_s_barrier();
        }
        {
            bf16x8 a_[2][2];
#pragma unroll
            for (int mi = 0; mi < 2; mi++) {
                a_[mi][0] = *(const bf16x8*)&Ac[(wm * 128 + (4 + mi) * 16 + fr) * 64 + cswz0];
                a_[mi][1] = *(const bf16x8*)&Ac[(wm * 128 + (4 + mi) * 16 + fr) * 64 + cswz1];
            }
            if (t + 2 < nt) stageB(t + 2, 1);
            __builtin_amdgcn_s_barrier();
            __builtin_amdgcn_s_setprio(1);
#pragma unroll
            for (int mi = 0; mi < 2; mi++)
#pragma unroll
                for (int n = 0; n < 4; n++)
#pragma unroll
                    for (int ks = 0; ks < 2; ks++)
                        acc[4 + mi][n] = __builtin_amdgcn_mfma_f32_16x16x32_bf16(a_[mi][ks], bfrag[n][ks], acc[4 + mi][n], 0, 0, 0);
            __builtin_amdgcn_s_setprio(0);
            __builtin_amdgcn_s_barrier();
        }
        {
            bf16x8 a_[2][2];
#pragma unroll
            for (int mi = 0; mi < 2; mi++) {
                a_[mi][0] = *(const bf16x8*)&Ac[(wm * 128 + (6 + mi) * 16 + fr) * 64 + cswz0];
                a_[mi][1] = *(const bf16x8*)&Ac[(wm * 128 + (6 + mi) * 16 + fr) * 64 + cswz1];
            }
            __builtin_amdgcn_s_barrier();
            __builtin_amdgcn_s_setprio(1);
#pragma unroll
            for (int mi = 0; mi < 2; mi++)
#pragma unroll
                for (int n = 0; n < 4; n++)
#pragma unroll
                    for (int ks = 0; ks < 2; ks++)
                        acc[6 + mi][n] = __builtin_amdgcn_mfma_f32_16x16x32_bf16(a_[mi][ks], bfrag[n][ks], acc[6 + mi][n], 0, 0, 0);
            __builtin_amdgcn_s_setprio(0);
            if (t + 2 < nt)
                asm volatile("s_waitcnt vmcnt(4)" ::: "memory");
            else if (t + 1 < nt)
                asm volatile("s_waitcnt vmcnt(0)" ::: "memory");
            __builtin_amdgcn_s_barrier();
        }
    }

#pragma unroll
    for (int mf = 0; mf < 8; mf++) {
        float lsum[4] = {0.f, 0.f, 0.f, 0.f};
#pragma unroll
        for (int n = 0; n < 4; n++) {
            int col = col0 + wn * 64 + n * 16 + fr;
            bool ok = (col < N);
#pragma unroll
            for (int r = 0; r < 4; r++) {
                int row = row0 + wm * 128 + mf * 16 + g * 4 + r;
                float v = acc[mf][n][r];
                if (ok) {
                    Cout[(size_t)row * N + col] = v;
                    lsum[r] += __expf(v);
                }
            }
        }
#pragma unroll
        for (int r = 0; r < 4; r++) {
            float s = lsum[r];
#pragma unroll
            for (int o = 1; o < 16; o <<= 1) s += __shfl_xor(s, o, 64);
            if (fr == 0)
                atomicAdd(&rowsum[row0 + wm * 128 + mf * 16 + g * 4 + r], s);
        }
    }
}

// ---------------------------------------------------------------- flash attention (barrier-free)
__global__ __launch_bounds__(256) void attn_kernel(
    const bf16* __restrict__ qkv, const bf16* __restrict__ vT, bf16* __restrict__ y)
{
    int qt = (int)(gridDim.x - 1 - blockIdx.x), h = blockIdx.y, b = blockIdx.z;
    const size_t rs = 3 * D_MODEL;
    int tid = threadIdx.x, lane = tid & 63, wid = tid >> 6;
    int fr = lane & 15, g = lane >> 4;
    int wq = qt * 64 + wid * 16;                 // wave's q-row base

    const bf16* qb = qkv + (size_t)b * SEQ * rs + h * 64;
    const bf16* kb = qb + D_MODEL;
    const bf16* vb = vT + ((size_t)(b * N_HEAD + h) * 64) * SEQ;

    __shared__ bf16 Ps[4][16][72];

    bf16x8 aq[2];
#pragma unroll
    for (int kk = 0; kk < 2; kk++)
        aq[kk] = *(const bf16x8*)&qb[(size_t)(wq + fr) * rs + kk * 32 + g * 8];

    f32x4 acco[4] = {};
    float mrow[4], lrow[4];
#pragma unroll
    for (int r = 0; r < 4; r++) { mrow[r] = -1e30f; lrow[r] = 0.f; }

    int jmax = qt * 64;
    for (int j0 = 0; j0 <= jmax; j0 += 64) {
        f32x4 accs[4] = {};
#pragma unroll
        for (int n = 0; n < 4; n++)
#pragma unroll
            for (int kk = 0; kk < 2; kk++) {
                bf16x8 bk = *(const bf16x8*)&kb[(size_t)(j0 + n * 16 + fr) * rs + kk * 32 + g * 8];
                accs[n] = __builtin_amdgcn_mfma_f32_16x16x32_bf16(aq[kk], bk, accs[n], 0, 0, 0);
            }

        bool diag = (j0 == jmax);
#pragma unroll
        for (int n = 0; n < 4; n++) {
            int jc = j0 + n * 16 + fr;
#pragma unroll
            for (int r = 0; r < 4; r++) {
                float sv = accs[n][r] * 0.125f;
                if (diag) { int irow = wq + g * 4 + r; if (jc > irow) sv = -1e30f; }
                accs[n][r] = sv;
            }
        }

        float pscale[4];
#pragma unroll
        for (int r = 0; r < 4; r++) {
            float pm = fmaxf(fmaxf(accs[0][r], accs[1][r]), fmaxf(accs[2][r], accs[3][r]));
#pragma unroll
            for (int o = 1; o < 16; o <<= 1) pm = fmaxf(pm, __shfl_xor(pm, o, 64));
            float mnew = fmaxf(mrow[r], pm);
            float corr = __expf(mrow[r] - mnew);
            mrow[r] = mnew;
            float ls = 0.f;
#pragma unroll
            for (int n = 0; n < 4; n++) {
                float p = __expf(accs[n][r] - mnew);
                accs[n][r] = p; ls += p;
            }
#pragma unroll
            for (int o = 1; o < 16; o <<= 1) ls += __shfl_xor(ls, o, 64);
            lrow[r] = lrow[r] * corr + ls;
            pscale[r] = corr;
        }
#pragma unroll
        for (int n = 0; n < 4; n++)
#pragma unroll
            for (int r = 0; r < 4; r++) acco[n][r] *= pscale[r];

#pragma unroll
        for (int n = 0; n < 4; n++)
#pragma unroll
            for (int r = 0; r < 4; r++)
                Ps[wid][g * 4 + r][n * 16 + fr] = (bf16)accs[n][r];

        bf16x8 ap[2];
#pragma unroll
        for (int kk = 0; kk < 2; kk++)
            ap[kk] = *(const bf16x8*)&Ps[wid][fr][kk * 32 + g * 8];
#pragma unroll
        for (int kk = 0; kk < 2; kk++)
#pragma unroll
            for (int n = 0; n < 4; n++) {
                bf16x8 bv = *(const bf16x8*)&vb[(size_t)(n * 16 + fr) * SEQ + j0 + kk * 32 + g * 8];
                acco[n] = __builtin_amdgcn_mfma_f32_16x16x32_bf16(ap[kk], bv, acco[n], 0, 0, 0);
            }
    }

    bf16* yb = y + (size_t)b * SEQ * D_MODEL + h * 64;
#pragma unroll
    for (int n = 0; n < 4; n++)
#pragma unroll
        for (int r = 0; r < 4; r++) {
            int row = wq + g * 4 + r;
            yb[(size_t)row * D_MODEL + n * 16 + fr] = (bf16)(acco[n][r] / lrow[r]);
        }
}

// ---------------------------------------------------------------- loss finalize
__global__ __launch_bounds__(256) void loss_nll_kernel(
    const float* __restrict__ logits, const float* __restrict__ rowsum,
    const int* __restrict__ tgt, float* __restrict__ accum)
{
    int row = blockIdx.x * 256 + threadIdx.x;
    if (row >= MROWS) return;
    int t = tgt[row];
    if (t >= 0) {
        float nll = logf(rowsum[row]) - logits[(size_t)row * VOCAB + t];
        atomicAdd(accum, nll);
        atomicAdd(accum + 1, 1.f);
    }
}

__global__ void loss_final_kernel(const float* __restrict__ accum, float* __restrict__ out)
{
    out[0] = accum[0] / fmaxf(accum[1], 1.f);
}

// ---------------------------------------------------------------- launch
extern "C" void kernel_launch(void* const* d_in, const int* in_sizes, int n_in,
                              void* d_out, int out_size, void* d_ws, size_t ws_size,
                              hipStream_t stream)
{
    const int*   feat  = (const int*)d_in[0];
    const int*   tgt   = (const int*)d_in[1];
    const float* tok   = (const float*)d_in[2];
    const float* pos   = (const float*)d_in[3];
    const float* ln1w  = (const float*)d_in[4];
    const float* ln1b  = (const float*)d_in[5];
    const float* attnw = (const float*)d_in[6];
    const float* attnb = (const float*)d_in[7];
    const float* projw = (const float*)d_in[8];
    const float* projb = (const float*)d_in[9];
    const float* ln2w  = (const float*)d_in[10];
    const float* ln2b  = (const float*)d_in[11];
    const float* fw1   = (const float*)d_in[12];
    const float* fb1   = (const float*)d_in[13];
    const float* fw2   = (const float*)d_in[14];
    const float* fb2   = (const float*)d_in[15];
    const float* lnfw  = (const float*)d_in[16];
    const float* lnfb  = (const float*)d_in[17];
    const float* finw  = (const float*)d_in[18];

    char* ws = (char*)d_ws;
    size_t off = 0;
    auto alloc = [&](size_t bytes) -> void* {
        void* p = ws + off; off += (bytes + 255) & ~(size_t)255; return p;
    };
    float* x     = (float*)alloc((size_t)MROWS * D_MODEL * 4);
    bf16*  h     = (bf16*) alloc((size_t)MROWS * D_MODEL * 2);
    bf16*  big   = (bf16*) alloc((size_t)MROWS * 4 * D_MODEL * 2);   // qkv (3D) / ffn1 (4D)
    bf16*  ybuf  = (bf16*) alloc((size_t)MROWS * D_MODEL * 2);
    bf16*  vT    = (bf16*) alloc((size_t)BATCH * N_HEAD * 64 * SEQ * 2);
    bf16*  awt   = (bf16*) alloc((size_t)N_LAYER * 3 * D_MODEL * D_MODEL * 2);
    bf16*  pwt   = (bf16*) alloc((size_t)N_LAYER * D_MODEL * D_MODEL * 2);
    bf16*  f1wt  = (bf16*) alloc((size_t)N_LAYER * 4 * D_MODEL * D_MODEL * 2);
    bf16*  f2wt  = (bf16*) alloc((size_t)N_LAYER * 4 * D_MODEL * D_MODEL * 2);
    bf16*  fwt   = (bf16*) alloc((size_t)VOCAB * D_MODEL * 2);
    float* rowsum= (float*)alloc((size_t)MROWS * 4);
    float* accum = (float*)alloc(256);

    float* logits = (float*)d_out;
    float* lossp  = (float*)d_out + (size_t)MROWS * VOCAB;

    dim3 blk(256);
    // weight transposes (f32 [K,N] -> bf16 [N,K])
    transpose_conv_kernel<<<dim3(3 * D_MODEL / 32, D_MODEL / 32, N_LAYER), blk, 0, stream>>>(attnw, awt, D_MODEL, 3 * D_MODEL);
    transpose_conv_kernel<<<dim3(D_MODEL / 32, D_MODEL / 32, N_LAYER), blk, 0, stream>>>(projw, pwt, D_MODEL, D_MODEL);
    transpose_conv_kernel<<<dim3(4 * D_MODEL / 32, D_MODEL / 32, N_LAYER), blk, 0, stream>>>(fw1, f1wt, D_MODEL, 4 * D_MODEL);
    transpose_conv_kernel<<<dim3(D_MODEL / 32, 4 * D_MODEL / 32, N_LAYER), blk, 0, stream>>>(fw2, f2wt, 4 * D_MODEL, D_MODEL);
    transpose_conv_kernel<<<dim3((VOCAB + 31) / 32, D_MODEL / 32, 1), blk, 0, stream>>>(finw, fwt, D_MODEL, VOCAB);

    embed_kernel<<<MROWS, blk, 0, stream>>>(feat, tok, pos, x);

    for (int l = 0; l < N_LAYER; l++) {
        ln_kernel<<<MROWS / 4, blk, 0, stream>>>(x, ln1w + l * D_MODEL, ln1b + l * D_MODEL, h);
        gemm_kernel<true, false, 3, 1><<<dim3(MROWS / 128, (3 * D_MODEL) / 128), blk, 0, stream>>>(
            h, awt + (size_t)l * 3 * D_MODEL * D_MODEL, attnb + l * 3 * D_MODEL, big, vT,
            MROWS, 3 * D_MODEL, D_MODEL);
        attn_kernel<<<dim3(SEQ / 64, N_HEAD, BATCH), blk, 0, stream>>>(big, vT, ybuf);
        gemm_kernel<true, false, 2, 2><<<dim3(MROWS / 128, D_MODEL / 128, 2), blk, 0, stream>>>(
            ybuf, pwt + (size_t)l * D_MODEL * D_MODEL, projb + l * D_MODEL, x, nullptr,
            MROWS, D_MODEL, D_MODEL);
        ln_kernel<<<MROWS / 4, blk, 0, stream>>>(x, ln2w + l * D_MODEL, ln2b + l * D_MODEL, h);
        gemm_kernel<true, true, 1, 1><<<dim3(MROWS / 128, (4 * D_MODEL) / 128), blk, 0, stream>>>(
            h, f1wt + (size_t)l * 4 * D_MODEL * D_MODEL, fb1 + l * 4 * D_MODEL, big, nullptr,
            MROWS, 4 * D_MODEL, D_MODEL);
        gemm_kernel<true, false, 2, 2><<<dim3(MROWS / 128, D_MODEL / 128, 2), blk, 0, stream>>>(
            big, f2wt + (size_t)l * 4 * D_MODEL * D_MODEL, fb2 + l * D_MODEL, x, nullptr,
            MROWS, D_MODEL, 4 * D_MODEL);
    }

    ln_kernel<<<MROWS / 4, blk, 0, stream>>>(x, lnfw, lnfb, h);

    hipMemsetAsync(rowsum, 0, (size_t)MROWS * 4, stream);
    hipMemsetAsync(accum, 0, 8, stream);

    gemm256_logits_kernel<<<dim3(MROWS / 256, (VOCAB + 255) / 256), dim3(512), 0, stream>>>(
        h, fwt, logits, rowsum, VOCAB, D_MODEL);

    loss_nll_kernel<<<(MROWS + 255) / 256, blk, 0, stream>>>(logits, rowsum, tgt, accum);
    loss_final_kernel<<<1, 1, 0, stream>>>(accum, lossp);

    (void)in_sizes; (void)n_in; (void)out_size; (void)ws_size;
}